// Round 3
// baseline (399.867 us; speedup 1.0000x reference)
//
#include <hip/hip_runtime.h>
#include <hip/hip_bf16.h>
#include <cstddef>

#define NB  4
#define NC  256
#define NN  4096
#define DQK 32
#define MT  32      // query rows per flash block
#define JT  64      // key tile per iteration
#define SSTR 68     // Ss row stride fp32 words (272 B rows)
#define VSTR 72     // Vs row stride bf16

typedef __attribute__((ext_vector_type(8))) short short8;
typedef __attribute__((ext_vector_type(4))) float f32x4;

#define MFMA16(a, b, c) __builtin_amdgcn_mfma_f32_16x16x32_bf16((a), (b), (c), 0, 0, 0)

__device__ inline unsigned pk2bf(float a, float b) {
  __hip_bfloat162 h = __float22bfloat162_rn(make_float2(a, b));
  unsigned u;
  __builtin_memcpy(&u, &h, 4);
  return u;
}

// ---- prep: x[b][c][n] f32 -> xT[b][n][c] bf16 ; W{q,k,v} f32 -> W16[320][256] bf16 ----
__global__ __launch_bounds__(256) void prep_kernel(
    const float* __restrict__ x, const float* __restrict__ Wq,
    const float* __restrict__ Wk, const float* __restrict__ Wv,
    __hip_bfloat16* __restrict__ xT, __hip_bfloat16* __restrict__ W16) {
  const int t = threadIdx.x;
  if (blockIdx.y == 4) {                       // W convert duty
    const int flat = blockIdx.x * 4 + blockIdx.z;   // 0..255
#pragma unroll
    for (int rep = 0; rep < 2; ++rep) {
      if (rep == 1 && t >= 64) break;
      const int id = flat * 320 + rep * 256 + t;    // < 81920
      const int row = id >> 8, col = id & 255;
      const float val = (row < 32) ? Wq[row * 256 + col]
                      : (row < 64) ? Wk[(row - 32) * 256 + col]
                                   : Wv[(row - 64) * 256 + col];
      W16[id] = __hip_bfloat16(val);
    }
    return;
  }
  __shared__ float Ls[64 * 69];
  const int b = blockIdx.z, c0 = blockIdx.y * 64, n0 = blockIdx.x * 64;
  {
    const int cl = t >> 4;
    const int nl = (t & 15) * 4;
#pragma unroll
    for (int p = 0; p < 4; ++p) {
      const int c = cl + p * 16;
      float4 vv = *(const float4*)(x + ((size_t)(b * NC + c0 + c)) * NN + n0 + nl);
      float* d = &Ls[c * 69 + nl];
      d[0] = vv.x; d[1] = vv.y; d[2] = vv.z; d[3] = vv.w;
    }
  }
  __syncthreads();
  {
    const int nl = t >> 4;
    const int cl = (t & 15) * 4;
#pragma unroll
    for (int p = 0; p < 4; ++p) {
      const int n = nl + p * 16;
      const float a0 = Ls[(cl + 0) * 69 + n], a1 = Ls[(cl + 1) * 69 + n];
      const float a2 = Ls[(cl + 2) * 69 + n], a3 = Ls[(cl + 3) * 69 + n];
      *(uint2*)(xT + ((size_t)b * NN + n0 + n) * NC + c0 + cl) =
          make_uint2(pk2bf(a0, a1), pk2bf(a2, a3));
    }
  }
}

// ---- proj: MFMA GEMMs, 1 wave/block, no LDS/barriers ----
// og==0: q/k  D[n][o]=x.W^T  (A=xT rows n, B=W16 rows o)
// og>=1: v    D[c][n]=W.x    (A=W16 rows c, B=xT rows n)
__global__ __launch_bounds__(64) void proj_kernel(
    const __hip_bfloat16* __restrict__ xT, const __hip_bfloat16* __restrict__ W16,
    const float* __restrict__ bq, const float* __restrict__ bk,
    const float* __restrict__ bv, __hip_bfloat16* __restrict__ q,
    __hip_bfloat16* __restrict__ kT, __hip_bfloat16* __restrict__ v) {
  const int t = threadIdx.x;
  const int ln = t & 15, quad = t >> 4;
  const int b = blockIdx.z, og = blockIdx.y, n0 = blockIdx.x * 64;
  const __hip_bfloat16* xb = xT + ((size_t)b * NN + n0) * NC;

  f32x4 zero4 = {0.f, 0.f, 0.f, 0.f};
  f32x4 acc[4][4];
#pragma unroll
  for (int i = 0; i < 4; ++i)
#pragma unroll
    for (int j = 0; j < 4; ++j) acc[i][j] = zero4;

  if (og == 0) {
#pragma unroll 2
    for (int k0 = 0; k0 < NC; k0 += 32) {
      short8 af[4], bf[4];
#pragma unroll
      for (int nt = 0; nt < 4; ++nt)
        af[nt] = *(const short8*)(xb + (nt * 16 + ln) * NC + k0 + quad * 8);
#pragma unroll
      for (int ot = 0; ot < 4; ++ot)
        bf[ot] = *(const short8*)(W16 + (ot * 16 + ln) * NC + k0 + quad * 8);
#pragma unroll
      for (int nt = 0; nt < 4; ++nt)
#pragma unroll
        for (int ot = 0; ot < 4; ++ot)
          acc[nt][ot] = MFMA16(af[nt], bf[ot], acc[nt][ot]);
    }
    float bias[4];
#pragma unroll
    for (int ot = 0; ot < 4; ++ot)
      bias[ot] = (ot < 2) ? bq[ot * 16 + ln] : bk[(ot - 2) * 16 + ln];
#pragma unroll
    for (int nt = 0; nt < 4; ++nt)
#pragma unroll
      for (int ot = 0; ot < 4; ++ot)
#pragma unroll
        for (int r = 0; r < 4; ++r) {
          const int n = n0 + nt * 16 + quad * 4 + r;
          const float val = acc[nt][ot][r] + bias[ot];
          if (ot < 2)
            q[((size_t)b * NN + n) * DQK + ot * 16 + ln] = __hip_bfloat16(val);
          else
            kT[((size_t)b * NN + n) * DQK + (ot - 2) * 16 + ln] = __hip_bfloat16(val);
        }
  } else {
    const int c0 = (og - 1) * 64;
    const __hip_bfloat16* wb = W16 + (size_t)(64 + c0) * NC;
#pragma unroll 2
    for (int k0 = 0; k0 < NC; k0 += 32) {
      short8 af[4], bf[4];
#pragma unroll
      for (int ct = 0; ct < 4; ++ct)
        af[ct] = *(const short8*)(wb + (ct * 16 + ln) * NC + k0 + quad * 8);
#pragma unroll
      for (int nt = 0; nt < 4; ++nt)
        bf[nt] = *(const short8*)(xb + (nt * 16 + ln) * NC + k0 + quad * 8);
#pragma unroll
      for (int ct = 0; ct < 4; ++ct)
#pragma unroll
        for (int nt = 0; nt < 4; ++nt)
          acc[ct][nt] = MFMA16(af[ct], bf[nt], acc[ct][nt]);
    }
#pragma unroll
    for (int ct = 0; ct < 4; ++ct) {
      float bias[4];
#pragma unroll
      for (int r = 0; r < 4; ++r) bias[r] = bv[c0 + ct * 16 + quad * 4 + r];
#pragma unroll
      for (int nt = 0; nt < 4; ++nt)
#pragma unroll
        for (int r = 0; r < 4; ++r) {
          const int c = c0 + ct * 16 + quad * 4 + r;
          v[((size_t)b * NC + c) * NN + n0 + nt * 16 + ln] =
              __hip_bfloat16(acc[ct][nt][r] + bias[r]);
        }
    }
  }
}

// ---- MFMA flash attention, MT=32, V/K register prefetch ----
__global__ __launch_bounds__(256) void flash_kernel(
    const __hip_bfloat16* __restrict__ q, const __hip_bfloat16* __restrict__ kt,
    const __hip_bfloat16* __restrict__ v, const float* __restrict__ x,
    const float* __restrict__ gamma, float* __restrict__ out) {
  __shared__ __hip_bfloat16 Vs[NC * VSTR];   // 36864 B
  __shared__ float Ss[MT * SSTR];            //  8704 B; doubles as P bf16
  __shared__ float2 red2[256];
  __shared__ float mrow[MT], lrow[MT], arow[MT];

  const int t  = threadIdx.x;
  const int bi = blockIdx.x;
  const int xcd = bi & 7;                    // XCD id; pair of XCDs per batch
  const int b   = xcd >> 1;
  const int m0  = ((xcd & 1) * 64 + (bi >> 3)) * MT;

  const int w    = __builtin_amdgcn_readfirstlane(t >> 6);
  const int ln   = t & 15;
  const int quad = (t & 63) >> 4;

  short8 qa[2];
#pragma unroll
  for (int mt = 0; mt < 2; ++mt)
    qa[mt] = *(const short8*)(q + ((size_t)b * NN + m0 + mt * 16 + ln) * DQK + quad * 8);
  if (t < MT) { mrow[t] = -3.0e38f; lrow[t] = 0.f; }

  f32x4 zero4 = {0.f, 0.f, 0.f, 0.f};
  f32x4 acc[4][2];
#pragma unroll
  for (int ct = 0; ct < 4; ++ct)
#pragma unroll
    for (int mt = 0; mt < 2; ++mt) acc[ct][mt] = zero4;

  const int c0 = w * 64;
  const int sm = t >> 3;   // softmax row (32)
  const int sc = t & 7;    // softmax chunk (8 j each)

  // prefetch j0=0: V tile + K frag into registers
  const int vc = t >> 3;          // V row base (32 rows/pass)
  const int vj = (t & 7) * 8;     // j offset
  const __hip_bfloat16* vb = v + ((size_t)b * NC) * NN;
  uint4 vreg[8];
#pragma unroll
  for (int p = 0; p < 8; ++p)
    vreg[p] = *(const uint4*)(vb + (size_t)(vc + p * 32) * NN + vj);
  short8 kb = *(const short8*)(kt + ((size_t)b * NN + w * 16 + ln) * DQK + quad * 8);

  for (int j0 = 0; j0 < NN; j0 += JT) {
    __syncthreads();  // barA: prior PV reads of Vs/Ps done

    // V regs -> LDS
#pragma unroll
    for (int p = 0; p < 8; ++p)
      *(uint4*)&Vs[(vc + p * 32) * VSTR + vj] = vreg[p];

    // S = Q.K^T (each wave: its 16-j strip, 2 m-tiles)
    {
      f32x4 sf[2];
#pragma unroll
      for (int mt = 0; mt < 2; ++mt) sf[mt] = MFMA16(qa[mt], kb, zero4);
#pragma unroll
      for (int mt = 0; mt < 2; ++mt)
#pragma unroll
        for (int r = 0; r < 4; ++r)
          Ss[(mt * 16 + quad * 4 + r) * SSTR + w * 16 + ln] = sf[mt][r];
    }
    __syncthreads();  // bar1: Vs + Ss visible

    // prefetch next iter's V + K (consumed after next barA)
    const int jn = j0 + JT;
    if (jn < NN) {
#pragma unroll
      for (int p = 0; p < 8; ++p)
        vreg[p] = *(const uint4*)(vb + (size_t)(vc + p * 32) * NN + jn + vj);
      kb = *(const short8*)(kt + ((size_t)b * NN + jn + w * 16 + ln) * DQK + quad * 8);
    }

    // softmax pass 1: 8 j per thread
    float e[8], cm;
    {
      const float4* srow = (const float4*)&Ss[sm * SSTR + sc * 8];
      float4 s0 = srow[0], s1 = srow[1];
      float sv[8] = {s0.x, s0.y, s0.z, s0.w, s1.x, s1.y, s1.z, s1.w};
      cm = sv[0];
#pragma unroll
      for (int i = 1; i < 8; ++i) cm = fmaxf(cm, sv[i]);
      float cs = 0.f;
#pragma unroll
      for (int i = 0; i < 8; ++i) { e[i] = __expf(sv[i] - cm); cs += e[i]; }
      red2[t] = make_float2(cm, cs);
    }
    __syncthreads();  // bar2

    // softmax pass 2: combine 8 chunks, write P bf16 over Ss
    {
      const float m_old = mrow[sm];
      const float l_old = lrow[sm];
      float2 rr[8];
#pragma unroll
      for (int i = 0; i < 8; ++i) rr[i] = red2[sm * 8 + i];
      float mnew = m_old;
#pragma unroll
      for (int i = 0; i < 8; ++i) mnew = fmaxf(mnew, rr[i].x);
      float ts = 0.f;
#pragma unroll
      for (int i = 0; i < 8; ++i) ts += rr[i].y * __expf(rr[i].x - mnew);
      const float alpha = __expf(m_old - mnew);
      if (sc == 0) { mrow[sm] = mnew; lrow[sm] = l_old * alpha + ts; arow[sm] = alpha; }
      const float scale = __expf(cm - mnew);
      unsigned pk[4];
#pragma unroll
      for (int i = 0; i < 4; ++i)
        pk[i] = pk2bf(e[2 * i] * scale, e[2 * i + 1] * scale);
      *(uint4*)((char*)Ss + sm * (SSTR * 4) + sc * 16) =
          make_uint4(pk[0], pk[1], pk[2], pk[3]);
    }
    __syncthreads();  // bar3: P + arow visible

    // PV: O'[c][m] += V.P^T ; per wave 64c x 32m
    {
      float av[2];
#pragma unroll
      for (int mt = 0; mt < 2; ++mt) av[mt] = arow[mt * 16 + ln];
#pragma unroll
      for (int ct = 0; ct < 4; ++ct)
#pragma unroll
        for (int mt = 0; mt < 2; ++mt) acc[ct][mt] *= av[mt];

#pragma unroll
      for (int ks = 0; ks < 2; ++ks) {
        short8 va[4], pb[2];
#pragma unroll
        for (int ct = 0; ct < 4; ++ct)
          va[ct] = *(const short8*)&Vs[(c0 + ct * 16 + ln) * VSTR + ks * 32 + quad * 8];
#pragma unroll
        for (int mt = 0; mt < 2; ++mt)
          pb[mt] = *(const short8*)((const char*)Ss +
                     (mt * 16 + ln) * (SSTR * 4) + (ks * 32 + quad * 8) * 2);
#pragma unroll
        for (int ct = 0; ct < 4; ++ct)
#pragma unroll
          for (int mt = 0; mt < 2; ++mt)
            acc[ct][mt] = MFMA16(va[ct], pb[mt], acc[ct][mt]);
      }
    }
  }

  // epilogue
  const float g0 = gamma[0];
  float li[2];
#pragma unroll
  for (int mt = 0; mt < 2; ++mt) li[mt] = 1.f / lrow[mt * 16 + ln];
#pragma unroll
  for (int ct = 0; ct < 4; ++ct) {
#pragma unroll
    for (int r = 0; r < 4; ++r) {
      const int c = c0 + ct * 16 + quad * 4 + r;
      const float* xr = x + ((size_t)b * NC + c) * NN + m0;
      float* orow = out + ((size_t)b * NC + c) * NN + m0;
#pragma unroll
      for (int mt = 0; mt < 2; ++mt) {
        const int m = mt * 16 + ln;
        orow[m] = g0 * (acc[ct][mt][r] * li[mt]) + xr[m];
      }
    }
  }
}

extern "C" void kernel_launch(void* const* d_in, const int* in_sizes, int n_in,
                              void* d_out, int out_size, void* d_ws, size_t ws_size,
                              hipStream_t stream) {
  const float* x     = (const float*)d_in[0];
  const float* Wq    = (const float*)d_in[1];
  const float* bq    = (const float*)d_in[2];
  const float* Wk    = (const float*)d_in[3];
  const float* bk    = (const float*)d_in[4];
  const float* Wv    = (const float*)d_in[5];
  const float* bv    = (const float*)d_in[6];
  const float* gamma = (const float*)d_in[7];
  float* out = (float*)d_out;

  __hip_bfloat16* xT  = (__hip_bfloat16*)d_ws;               // [B][N][256]  8.4 MB
  __hip_bfloat16* W16 = xT + (size_t)NB * NN * NC;           // [320][256]   164 KB
  __hip_bfloat16* q   = W16 + (size_t)320 * NC;              // [B][N][32]   1 MB
  __hip_bfloat16* kT  = q + (size_t)NB * NN * DQK;           // [B][N][32]   1 MB
  __hip_bfloat16* v   = kT + (size_t)NB * NN * DQK;          // [B][C][N]    8.4 MB

  prep_kernel<<<dim3(NN / 64, 5, NB), dim3(256), 0, stream>>>(x, Wq, Wk, Wv, xT, W16);
  proj_kernel<<<dim3(NN / 64, 5, NB), dim3(64), 0, stream>>>(xT, W16, bq, bk, bv, q, kT, v);
  flash_kernel<<<dim3(NB * NN / MT), dim3(256), 0, stream>>>(q, kT, v, x, gamma, out);
}

// Round 4
// 211.111 us; speedup vs baseline: 1.8941x; 1.8941x over previous
//
#include <hip/hip_runtime.h>
#include <hip/hip_bf16.h>
#include <cstddef>

#define NB  4
#define NC  256
#define NN  4096
#define DQK 32
#define MT  64      // query rows per flash block (16 per wave)
#define JT  64      // key tile per iteration
#define PSTR 72     // P row stride in bf16 (36 words -> b128 reads at conflict floor)

typedef __attribute__((ext_vector_type(8))) short short8;
typedef __attribute__((ext_vector_type(4))) float f32x4;

#define MFMA16(a, b, c) __builtin_amdgcn_mfma_f32_16x16x32_bf16((a), (b), (c), 0, 0, 0)

__device__ inline unsigned pk2bf(float a, float b) {
  __hip_bfloat162 h = __float22bfloat162_rn(make_float2(a, b));
  unsigned u;
  __builtin_memcpy(&u, &h, 4);
  return u;
}

// ---- prep: x[b][c][n] f32 -> xT[b][n][c] bf16 ; W{q,k,v} f32 -> W16[320][256] bf16 ----
__global__ __launch_bounds__(256) void prep_kernel(
    const float* __restrict__ x, const float* __restrict__ Wq,
    const float* __restrict__ Wk, const float* __restrict__ Wv,
    __hip_bfloat16* __restrict__ xT, __hip_bfloat16* __restrict__ W16) {
  const int t = threadIdx.x;
  if (blockIdx.y == 4) {                       // W convert duty
    const int flat = blockIdx.x * 4 + blockIdx.z;   // 0..255
#pragma unroll
    for (int rep = 0; rep < 2; ++rep) {
      if (rep == 1 && t >= 64) break;
      const int id = flat * 320 + rep * 256 + t;    // < 81920
      const int row = id >> 8, col = id & 255;
      const float val = (row < 32) ? Wq[row * 256 + col]
                      : (row < 64) ? Wk[(row - 32) * 256 + col]
                                   : Wv[(row - 64) * 256 + col];
      W16[id] = __hip_bfloat16(val);
    }
    return;
  }
  __shared__ float Ls[64 * 69];
  const int b = blockIdx.z, c0 = blockIdx.y * 64, n0 = blockIdx.x * 64;
  {
    const int cl = t >> 4;
    const int nl = (t & 15) * 4;
#pragma unroll
    for (int p = 0; p < 4; ++p) {
      const int c = cl + p * 16;
      float4 vv = *(const float4*)(x + ((size_t)(b * NC + c0 + c)) * NN + n0 + nl);
      float* d = &Ls[c * 69 + nl];
      d[0] = vv.x; d[1] = vv.y; d[2] = vv.z; d[3] = vv.w;
    }
  }
  __syncthreads();
  {
    const int nl = t >> 4;
    const int cl = (t & 15) * 4;
#pragma unroll
    for (int p = 0; p < 4; ++p) {
      const int n = nl + p * 16;
      const float a0 = Ls[(cl + 0) * 69 + n], a1 = Ls[(cl + 1) * 69 + n];
      const float a2 = Ls[(cl + 2) * 69 + n], a3 = Ls[(cl + 3) * 69 + n];
      *(uint2*)(xT + ((size_t)b * NN + n0 + n) * NC + c0 + cl) =
          make_uint2(pk2bf(a0, a1), pk2bf(a2, a3));
    }
  }
}

// ---- proj: MFMA GEMMs, 1 wave/block, no LDS/barriers ----
__global__ __launch_bounds__(64) void proj_kernel(
    const __hip_bfloat16* __restrict__ xT, const __hip_bfloat16* __restrict__ W16,
    const float* __restrict__ bq, const float* __restrict__ bk,
    const float* __restrict__ bv, __hip_bfloat16* __restrict__ q,
    __hip_bfloat16* __restrict__ kT, __hip_bfloat16* __restrict__ v) {
  const int t = threadIdx.x;
  const int ln = t & 15, quad = t >> 4;
  const int b = blockIdx.z, og = blockIdx.y, n0 = blockIdx.x * 64;
  const __hip_bfloat16* xb = xT + ((size_t)b * NN + n0) * NC;

  f32x4 zero4 = {0.f, 0.f, 0.f, 0.f};
  f32x4 acc[4][4];
#pragma unroll
  for (int i = 0; i < 4; ++i)
#pragma unroll
    for (int j = 0; j < 4; ++j) acc[i][j] = zero4;

  if (og == 0) {
#pragma unroll 2
    for (int k0 = 0; k0 < NC; k0 += 32) {
      short8 af[4], bf[4];
#pragma unroll
      for (int nt = 0; nt < 4; ++nt)
        af[nt] = *(const short8*)(xb + (nt * 16 + ln) * NC + k0 + quad * 8);
#pragma unroll
      for (int ot = 0; ot < 4; ++ot)
        bf[ot] = *(const short8*)(W16 + (ot * 16 + ln) * NC + k0 + quad * 8);
#pragma unroll
      for (int nt = 0; nt < 4; ++nt)
#pragma unroll
        for (int ot = 0; ot < 4; ++ot)
          acc[nt][ot] = MFMA16(af[nt], bf[ot], acc[nt][ot]);
    }
    float bias[4];
#pragma unroll
    for (int ot = 0; ot < 4; ++ot)
      bias[ot] = (ot < 2) ? bq[ot * 16 + ln] : bk[(ot - 2) * 16 + ln];
#pragma unroll
    for (int nt = 0; nt < 4; ++nt)
#pragma unroll
      for (int ot = 0; ot < 4; ++ot)
#pragma unroll
        for (int r = 0; r < 4; ++r) {
          const int n = n0 + nt * 16 + quad * 4 + r;
          const float val = acc[nt][ot][r] + bias[ot];
          if (ot < 2)
            q[((size_t)b * NN + n) * DQK + ot * 16 + ln] = __hip_bfloat16(val);
          else
            kT[((size_t)b * NN + n) * DQK + (ot - 2) * 16 + ln] = __hip_bfloat16(val);
        }
  } else {
    const int c0 = (og - 1) * 64;
    const __hip_bfloat16* wb = W16 + (size_t)(64 + c0) * NC;
#pragma unroll 2
    for (int k0 = 0; k0 < NC; k0 += 32) {
      short8 af[4], bf[4];
#pragma unroll
      for (int ct = 0; ct < 4; ++ct)
        af[ct] = *(const short8*)(wb + (ct * 16 + ln) * NC + k0 + quad * 8);
#pragma unroll
      for (int nt = 0; nt < 4; ++nt)
        bf[nt] = *(const short8*)(xb + (nt * 16 + ln) * NC + k0 + quad * 8);
#pragma unroll
      for (int ct = 0; ct < 4; ++ct)
#pragma unroll
        for (int nt = 0; nt < 4; ++nt)
          acc[ct][nt] = MFMA16(af[ct], bf[nt], acc[ct][nt]);
    }
#pragma unroll
    for (int ct = 0; ct < 4; ++ct) {
      float bias[4];
#pragma unroll
      for (int r = 0; r < 4; ++r) bias[r] = bv[c0 + ct * 16 + quad * 4 + r];
#pragma unroll
      for (int nt = 0; nt < 4; ++nt)
#pragma unroll
        for (int r = 0; r < 4; ++r) {
          const int c = c0 + ct * 16 + quad * 4 + r;
          v[((size_t)b * NC + c) * NN + n0 + nt * 16 + ln] =
              __hip_bfloat16(acc[ct][nt][r] + bias[r]);
        }
    }
  }
}

// ---- wave-local flash: S in regs, in-wave softmax, 1 barrier/iter ----
// Wave w owns query rows [m0+w*16, m0+w*16+16); PV splits channels (wave w: c in [w*64, w*64+64)).
__global__ __launch_bounds__(256, 1) void flash_kernel(
    const __hip_bfloat16* __restrict__ q, const __hip_bfloat16* __restrict__ kt,
    const __hip_bfloat16* __restrict__ v, const float* __restrict__ x,
    const float* __restrict__ gamma, float* __restrict__ out) {
  __shared__ __hip_bfloat16 Ps[2][MT * PSTR];   // 18432 B, double-buffered
  __shared__ float arow[2][MT];
  __shared__ float lrow[MT];

  const int t  = threadIdx.x;
  const int bi = blockIdx.x;
  // XCD swizzle: XCD pair {2b, 2b+1} serves batch b -> V slice 2 MB resident in 8 MB L2
  const int b  = (bi & 7) >> 1;
  const int m0 = (((bi & 1) * 32) + (bi >> 3)) * MT;   // 64 m-tiles per batch

  const int w    = __builtin_amdgcn_readfirstlane(t >> 6);
  const int ln   = t & 15;
  const int quad = (t & 63) >> 4;

  const __hip_bfloat16* kb_base = kt + (size_t)b * NN * DQK;
  const __hip_bfloat16* v_base  = v + (size_t)b * NC * NN;

  // Q A-frag for this wave's 16 rows
  const short8 qa =
      *(const short8*)(q + ((size_t)b * NN + m0 + w * 16 + ln) * DQK + quad * 8);

  float mreg[4], lreg[4];
#pragma unroll
  for (int r = 0; r < 4; ++r) { mreg[r] = -3.0e38f; lreg[r] = 0.f; }

  f32x4 zero4 = {0.f, 0.f, 0.f, 0.f};
  f32x4 acc[4][4];   // [ct][mt]: rows c = w*64+ct*16+quad*4+r, cols m = mt*16+ln
#pragma unroll
  for (int ct = 0; ct < 4; ++ct)
#pragma unroll
    for (int mt = 0; mt < 4; ++mt) acc[ct][mt] = zero4;

  // preload K B-frags for j0 = 0
  short8 kb[4];
#pragma unroll
  for (int jt = 0; jt < 4; ++jt)
    kb[jt] = *(const short8*)(kb_base + (size_t)(jt * 16 + ln) * DQK + quad * 8);

  for (int it = 0; it < NN / JT; ++it) {
    const int j0  = it * JT;
    const int buf = it & 1;

    // ---- S = Q.K^T for this wave's 16 rows x 64 j (stays in registers) ----
    f32x4 sf[4];
#pragma unroll
    for (int jt = 0; jt < 4; ++jt) sf[jt] = MFMA16(qa, kb[jt], zero4);

    // ---- prefetch next K + this iter's V A-frags (drained by the barrier) ----
    const int jn = j0 + JT;
    short8 kbn[4];
    if (jn < NN) {
#pragma unroll
      for (int jt = 0; jt < 4; ++jt)
        kbn[jt] = *(const short8*)(kb_base + (size_t)(jn + jt * 16 + ln) * DQK + quad * 8);
    }
    short8 va[4][2];
#pragma unroll
    for (int ct = 0; ct < 4; ++ct)
#pragma unroll
      for (int ks = 0; ks < 2; ++ks)
        va[ct][ks] = *(const short8*)(v_base +
            (size_t)(w * 64 + ct * 16 + ln) * NN + j0 + ks * 32 + quad * 8);

    // ---- wave-local online softmax (rows quad*4+r, cols jt*16+ln) ----
    float rmax[4];
#pragma unroll
    for (int r = 0; r < 4; ++r)
      rmax[r] = fmaxf(fmaxf(sf[0][r], sf[1][r]), fmaxf(sf[2][r], sf[3][r]));
#pragma unroll
    for (int off = 1; off < 16; off <<= 1)
#pragma unroll
      for (int r = 0; r < 4; ++r)
        rmax[r] = fmaxf(rmax[r], __shfl_xor(rmax[r], off));
    float alpha[4];
#pragma unroll
    for (int r = 0; r < 4; ++r) {
      const float mn = fmaxf(mreg[r], rmax[r]);
      alpha[r] = __expf(mreg[r] - mn);
      mreg[r] = mn;
    }
    float e[4][4], rsum[4];
#pragma unroll
    for (int r = 0; r < 4; ++r) rsum[r] = 0.f;
#pragma unroll
    for (int jt = 0; jt < 4; ++jt)
#pragma unroll
      for (int r = 0; r < 4; ++r) {
        e[jt][r] = __expf(sf[jt][r] - mreg[r]);
        rsum[r] += e[jt][r];
      }
#pragma unroll
    for (int off = 1; off < 16; off <<= 1)
#pragma unroll
      for (int r = 0; r < 4; ++r) rsum[r] += __shfl_xor(rsum[r], off);
#pragma unroll
    for (int r = 0; r < 4; ++r) lreg[r] = lreg[r] * alpha[r] + rsum[r];

    // ---- write P tile [m][j] bf16 + alpha exchange ----
#pragma unroll
    for (int jt = 0; jt < 4; ++jt)
#pragma unroll
      for (int r = 0; r < 4; ++r)
        Ps[buf][(w * 16 + quad * 4 + r) * PSTR + jt * 16 + ln] = __hip_bfloat16(e[jt][r]);
    if (ln == 0) {
#pragma unroll
      for (int r = 0; r < 4; ++r) arow[buf][w * 16 + quad * 4 + r] = alpha[r];
    }
    __syncthreads();   // single barrier: P[buf]+arow[buf] visible; prior buf reuse guarded

    // ---- PV: O'[c][m] += V.P^T ; wave covers c in [w*64, w*64+64) ----
    float av[4];
#pragma unroll
    for (int mt = 0; mt < 4; ++mt) av[mt] = arow[buf][mt * 16 + ln];
#pragma unroll
    for (int ct = 0; ct < 4; ++ct)
#pragma unroll
      for (int mt = 0; mt < 4; ++mt) acc[ct][mt] *= av[mt];

#pragma unroll
    for (int ks = 0; ks < 2; ++ks) {
      short8 pb[4];
#pragma unroll
      for (int mt = 0; mt < 4; ++mt)
        pb[mt] = *(const short8*)&Ps[buf][(mt * 16 + ln) * PSTR + ks * 32 + quad * 8];
#pragma unroll
      for (int ct = 0; ct < 4; ++ct)
#pragma unroll
        for (int mt = 0; mt < 4; ++mt)
          acc[ct][mt] = MFMA16(va[ct][ks], pb[mt], acc[ct][mt]);
    }

#pragma unroll
    for (int jt = 0; jt < 4; ++jt) kb[jt] = kbn[jt];
  }

  // ---- l exchange + epilogue: out[b][c][m] = gamma*(O'/l) + x ----
  if (ln == 0) {
#pragma unroll
    for (int r = 0; r < 4; ++r) lrow[w * 16 + quad * 4 + r] = lreg[r];
  }
  __syncthreads();

  const float g0 = gamma[0];
  float li[4];
#pragma unroll
  for (int mt = 0; mt < 4; ++mt) li[mt] = 1.f / lrow[mt * 16 + ln];
#pragma unroll
  for (int ct = 0; ct < 4; ++ct) {
#pragma unroll
    for (int r = 0; r < 4; ++r) {
      const int c = w * 64 + ct * 16 + quad * 4 + r;
      const float* xr = x + ((size_t)b * NC + c) * NN + m0;
      float* orow = out + ((size_t)b * NC + c) * NN + m0;
#pragma unroll
      for (int mt = 0; mt < 4; ++mt) {
        const int m = mt * 16 + ln;
        orow[m] = g0 * (acc[ct][mt][r] * li[mt]) + xr[m];
      }
    }
  }
}

extern "C" void kernel_launch(void* const* d_in, const int* in_sizes, int n_in,
                              void* d_out, int out_size, void* d_ws, size_t ws_size,
                              hipStream_t stream) {
  const float* x     = (const float*)d_in[0];
  const float* Wq    = (const float*)d_in[1];
  const float* bq    = (const float*)d_in[2];
  const float* Wk    = (const float*)d_in[3];
  const float* bk    = (const float*)d_in[4];
  const float* Wv    = (const float*)d_in[5];
  const float* bv    = (const float*)d_in[6];
  const float* gamma = (const float*)d_in[7];
  float* out = (float*)d_out;

  __hip_bfloat16* xT  = (__hip_bfloat16*)d_ws;               // [B][N][256]  8.4 MB
  __hip_bfloat16* W16 = xT + (size_t)NB * NN * NC;           // [320][256]   164 KB
  __hip_bfloat16* q   = W16 + (size_t)320 * NC;              // [B][N][32]   1 MB
  __hip_bfloat16* kT  = q + (size_t)NB * NN * DQK;           // [B][N][32]   1 MB
  __hip_bfloat16* v   = kT + (size_t)NB * NN * DQK;          // [B][C][N]    8.4 MB

  prep_kernel<<<dim3(NN / 64, 5, NB), dim3(256), 0, stream>>>(x, Wq, Wk, Wv, xT, W16);
  proj_kernel<<<dim3(NN / 64, 5, NB), dim3(64), 0, stream>>>(xT, W16, bq, bk, bv, q, kT, v);
  flash_kernel<<<dim3(NB * NN / MT), dim3(256), 0, stream>>>(q, kT, v, x, gamma, out);
}